// Round 5
// baseline (171.028 us; speedup 1.0000x reference)
//
#include <hip/hip_runtime.h>
#include <math.h>
#include <stdint.h>

#define T_SEQ 2048
#define BATCH 4
#define DMODEL 128
#define DFF 512
#define NHEAD 8
#define EHEAD 16

#define RSQRT_T 0.022097086912079608f
#define QSCALE (0.022097086912079608f * 1.4426950408889634f)   // fold log2(e): use exp2

typedef __attribute__((ext_vector_type(8))) short bf16x8;
typedef __attribute__((ext_vector_type(4))) short bf16x4;
typedef __attribute__((ext_vector_type(4))) float f32x4;
typedef __attribute__((ext_vector_type(4))) int i32x4;

__device__ __forceinline__ short f2bf(float f) {            // RNE
    uint32_t u = __float_as_uint(f);
    u = u + 0x7FFF + ((u >> 16) & 1);
    return (short)(u >> 16);
}
__device__ __forceinline__ short bftrunc(float f) {         // truncate (cheap)
    return (short)(__float_as_uint(f) >> 16);
}
__device__ __forceinline__ float bf2f(short s) {
    return __uint_as_float(((uint32_t)(unsigned short)s) << 16);
}

// ---------------------------------------------------------------------------
// K0: xpe = x + PE; weights -> bf16 transposed; zero the K-pad halves of Qp/Kp
// ---------------------------------------------------------------------------
__global__ __launch_bounds__(256) void k_pre(const float* __restrict__ x,
                                             const float* __restrict__ WQ,
                                             const float* __restrict__ WK,
                                             const float* __restrict__ WV,
                                             const float* __restrict__ W1,
                                             const float* __restrict__ W2,
                                             float* __restrict__ xpe,
                                             short* __restrict__ xpe16,
                                             short* __restrict__ Wqkvt,
                                             short* __restrict__ W1t,
                                             short* __restrict__ W2t,
                                             short* __restrict__ Qp,
                                             short* __restrict__ Kp) {
    int bid = blockIdx.x;
    int tid = threadIdx.x;
    if (bid < 4096) {                       // PE over B*T*D = 1M
        int idx = bid * 256 + tid;
        int f = idx & (DMODEL - 1);
        int t = (idx >> 7) & (T_SEQ - 1);
        float dv = __expf(-(float)(f & ~1) * (9.210340371976184f / 128.0f));
        float ang = (float)t * dv;
        float pe = (f & 1) ? __cosf(ang) : __sinf(ang);
        float v = x[idx] + pe;
        xpe[idx] = v;
        xpe16[idx] = f2bf(v);
    } else if (bid < 4288) {                // WQ/WK/WV -> [n][k] bf16
        int m = (bid - 4096) >> 6;
        int o = ((bid - 4096) & 63) * 256 + tid;      // 0..16383
        int n = o >> 7, k = o & 127;
        const float* W = (m == 0) ? WQ : (m == 1) ? WK : WV;
        Wqkvt[m * 16384 + o] = f2bf(W[k * 128 + n]);
    } else if (bid < 4544) {                // W1 [128][512] -> W1t [512][128]
        int o = (bid - 4288) * 256 + tid;   // 0..65535
        int n = o >> 7, k = o & 127;
        W1t[o] = f2bf(W1[k * 512 + n]);
    } else if (bid < 4800) {                // W2 [512][128] -> W2t [128][512]
        int o = (bid - 4544) * 256 + tid;   // 0..65535
        int n = o >> 9, k = o & 511;
        W2t[o] = f2bf(W2[k * 128 + n]);
    } else {                                // zero Qp/Kp (2 x 2NTD shorts = 8MB)
        size_t o = (size_t)(bid - 4800) * 256 + tid;  // 0..524287, 16B units
        i32x4 zz = {0, 0, 0, 0};
        short* base = (o < 262144) ? Qp : Kp;
        size_t oo = (o & 262143) * 8;
        *(i32x4*)(base + oo) = zz;
    }
}

// ---------------------------------------------------------------------------
// K1: QKV projection: bf16 MFMA GEMM, W in registers (Wt[n][k] bf16).
// z=0: Qp[hb][t][32] (low 16) *= QSCALE; z=1: Kp[hb][t][32]; z=2: Vs[hb][e][T]
// block 256 (4 waves x 16 rows = 64 rows), grid (128, 3)
// ---------------------------------------------------------------------------
__global__ __launch_bounds__(256) void k_qkv(const short* __restrict__ xpe16,
                                             const short* __restrict__ Wqkvt,
                                             short* __restrict__ Qp,
                                             short* __restrict__ Kp,
                                             short* __restrict__ Vs) {
    int z = blockIdx.y;
    const short* Wt = Wqkvt + z * 16384;
    int wave = threadIdx.x >> 6, lane = threadIdx.x & 63;
    int g = lane >> 4, c = lane & 15;
    int row0 = blockIdx.x * 64 + wave * 16;

    bf16x8 wf[8][4];
#pragma unroll
    for (int nt = 0; nt < 8; ++nt)
#pragma unroll
        for (int kk = 0; kk < 4; ++kk)
            wf[nt][kk] = *(const bf16x8*)(Wt + (nt * 16 + c) * 128 + kk * 32 + 8 * g);

    bf16x8 af[4];
#pragma unroll
    for (int kk = 0; kk < 4; ++kk)
        af[kk] = *(const bf16x8*)(xpe16 + (size_t)(row0 + c) * 128 + kk * 32 + 8 * g);

    f32x4 acc[8];
#pragma unroll
    for (int nt = 0; nt < 8; ++nt) acc[nt] = (f32x4){0.f, 0.f, 0.f, 0.f};
#pragma unroll
    for (int kk = 0; kk < 4; ++kk)
#pragma unroll
        for (int nt = 0; nt < 8; ++nt)
            acc[nt] = __builtin_amdgcn_mfma_f32_16x16x32_bf16(af[kk], wf[nt][kk], acc[nt], 0, 0, 0);

    int b = row0 >> 11;
    int t0 = (row0 & (T_SEQ - 1)) + 4 * g;
    if (z < 2) {
        short* dst = (z == 0) ? Qp : Kp;
        float sc = (z == 0) ? QSCALE : 1.0f;
#pragma unroll
        for (int nt = 0; nt < 8; ++nt) {
            int hb = nt * 4 + b;
#pragma unroll
            for (int r = 0; r < 4; ++r)
                dst[(size_t)(hb * T_SEQ + t0 + r) * 32 + c] = f2bf(acc[nt][r] * sc);
        }
    } else {
#pragma unroll
        for (int nt = 0; nt < 8; ++nt) {
            int hb = nt * 4 + b;
            bf16x4 v;
#pragma unroll
            for (int r = 0; r < 4; ++r) v[r] = f2bf(acc[nt][r]);
            *(bf16x4*)(Vs + (size_t)(hb * 16 + c) * T_SEQ + t0) = v;
        }
    }
}

// ---------------------------------------------------------------------------
// K2a: partial column sums. Task = (hb, k-slot of 32 cols, q-chunk of 256).
// psum[hb][qc][ks][32] = sum over chunk's q (causal) of exp2(S'[q,k])
// grid (16, 8, 32): ks = bx*4+wave, qc = by, hb = bz. block 256.
// ---------------------------------------------------------------------------
__global__ __launch_bounds__(256) void k_csum_part(const short* __restrict__ Qp,
                                                   const short* __restrict__ Kp,
                                                   float* __restrict__ psum) {
    int wave = threadIdx.x >> 6, lane = threadIdx.x & 63;
    int g = lane >> 4, c = lane & 15;
    int ks = blockIdx.x * 4 + wave;
    int qc = blockIdx.y;
    int hb = blockIdx.z;
    int k0 = ks * 32;
    int qcs = qc * 256;
    if (k0 >= qcs + 256) return;            // chunk entirely above diagonal
    const size_t hbT = (size_t)hb * T_SEQ;
    const f32x4 z = {0.f, 0.f, 0.f, 0.f};

    bf16x8 kfA = *(const bf16x8*)(Kp + (hbT + k0 + c) * 32 + 8 * g);
    bf16x8 kfB = *(const bf16x8*)(Kp + (hbT + k0 + 16 + c) * 32 + 8 * g);

    float csA = 0.f, csB = 0.f;
    int q0;
    if (k0 >= qcs) {                        // diagonal tiles live in this chunk
        {   // q-tile at k0: A diagonal, B empty
            bf16x8 qf = *(const bf16x8*)(Qp + (hbT + k0 + c) * 32 + 8 * g);
            f32x4 sA = __builtin_amdgcn_mfma_f32_16x16x32_bf16(qf, kfA, z, 0, 0, 0);
#pragma unroll
            for (int r = 0; r < 4; ++r)
                csA += (4 * g + r >= c) ? exp2f(sA[r]) : 0.f;
        }
        {   // q-tile at k0+16: A full, B diagonal
            bf16x8 qf = *(const bf16x8*)(Qp + (hbT + k0 + 16 + c) * 32 + 8 * g);
            f32x4 sA = __builtin_amdgcn_mfma_f32_16x16x32_bf16(qf, kfA, z, 0, 0, 0);
            f32x4 sB = __builtin_amdgcn_mfma_f32_16x16x32_bf16(qf, kfB, z, 0, 0, 0);
#pragma unroll
            for (int r = 0; r < 4; ++r) {
                csA += exp2f(sA[r]);
                csB += (4 * g + r >= c) ? exp2f(sB[r]) : 0.f;
            }
        }
        q0 = k0 + 32;
    } else {
        q0 = qcs;
    }
    int qend = qcs + 256;
    if (q0 < qend) {
        bf16x8 qf = *(const bf16x8*)(Qp + (hbT + q0 + c) * 32 + 8 * g);
        for (; q0 < qend; q0 += 16) {
            // prefetch next (1-tile overread at the very end stays in ws)
            bf16x8 nq = *(const bf16x8*)(Qp + (hbT + q0 + 16 + c) * 32 + 8 * g);
            f32x4 sA = __builtin_amdgcn_mfma_f32_16x16x32_bf16(qf, kfA, z, 0, 0, 0);
            f32x4 sB = __builtin_amdgcn_mfma_f32_16x16x32_bf16(qf, kfB, z, 0, 0, 0);
#pragma unroll
            for (int r = 0; r < 4; ++r) {
                csA += exp2f(sA[r]);
                csB += exp2f(sB[r]);
            }
            qf = nq;
        }
    }
    csA += __shfl_xor(csA, 16);
    csA += __shfl_xor(csA, 32);
    csB += __shfl_xor(csB, 16);
    csB += __shfl_xor(csB, 32);
    if (lane < 32)
        psum[((size_t)(hb * 8 + qc) * 64 + ks) * 32 + lane] =
            (lane < 16) ? csA : csB;
}

// ---------------------------------------------------------------------------
// K2b: reduce partials -> inv, scale V columns. grid (16, 32), block 256.
// ---------------------------------------------------------------------------
__global__ __launch_bounds__(256) void k_csum_fin(const float* __restrict__ psum,
                                                  short* __restrict__ Vs) {
    __shared__ float invl[128];
    int hb = blockIdx.y;
    int t = threadIdx.x;
    if (t < 128) {
        int k = blockIdx.x * 128 + t;
        int ks = k >> 5, j = k & 31;
        float s = 0.f;
        for (int qc = ks >> 3; qc < 8; ++qc)
            s += psum[((size_t)(hb * 8 + qc) * 64 + ks) * 32 + j];
        invl[t] = 1.0f / s;
    }
    __syncthreads();
    int e = t >> 4, kk = (t & 15) * 8;
    size_t vo = (size_t)(hb * 16 + e) * T_SEQ + blockIdx.x * 128 + kk;
    bf16x8 v = *(bf16x8*)(Vs + vo);
    bf16x8 o;
#pragma unroll
    for (int j = 0; j < 8; ++j) o[j] = f2bf(bf2f(v[j]) * invl[kk + j]);
    *(bf16x8*)(Vs + vo) = o;
}

// ---------------------------------------------------------------------------
// K3: attention output. Each wave owns 16 q-rows; K/V fragments streamed from
// L2 with one-iteration register prefetch; no LDS, no barriers, no masking in
// the main loop (diagonal tile peeled). V is pre-scaled by 1/c.
// grid (32, 32): s = bx*4+wave in [0,128), q0 = (127-s)*16 (longest first).
// ---------------------------------------------------------------------------
__global__ __launch_bounds__(256) void k_attn(const short* __restrict__ Qp,
                                              const short* __restrict__ Kp,
                                              const short* __restrict__ Vs,
                                              short* __restrict__ AObf) {
    int hb = blockIdx.y, h = hb >> 2, b = hb & 3;
    int wave = threadIdx.x >> 6, lane = threadIdx.x & 63;
    int g = lane >> 4, c = lane & 15;
    int s = blockIdx.x * 4 + wave;
    int q0 = (127 - s) * 16;
    const size_t hbT = (size_t)hb * T_SEQ;
    const f32x4 z = {0.f, 0.f, 0.f, 0.f};

    bf16x8 qf = *(const bf16x8*)(Qp + (hbT + q0 + c) * 32 + 8 * g);
    const short* vb = Vs + (size_t)(hb * 16 + c) * T_SEQ;
    const short* kb = Kp + (hbT + c) * 32 + 8 * g;

    int nfull = q0 >> 5;                    // full 32-k tiles before diagonal

    f32x4 acc = {0.f, 0.f, 0.f, 0.f};
    bf16x8 kf0 = *(const bf16x8*)(kb);
    bf16x8 kf1 = *(const bf16x8*)(kb + 16 * 32);
    bf16x4 v0 = *(const bf16x4*)(vb + 4 * g);
    bf16x4 v1 = *(const bf16x4*)(vb + 16 + 4 * g);

    for (int it = 0; it < nfull; ++it) {
        int k0n = (it + 1) * 32;
        bf16x8 nk0 = *(const bf16x8*)(kb + (size_t)k0n * 32);
        bf16x8 nk1 = *(const bf16x8*)(kb + (size_t)(k0n + 16) * 32);
        bf16x4 nv0 = *(const bf16x4*)(vb + k0n + 4 * g);
        bf16x4 nv1 = *(const bf16x4*)(vb + k0n + 16 + 4 * g);

        f32x4 s0 = __builtin_amdgcn_mfma_f32_16x16x32_bf16(kf0, qf, z, 0, 0, 0);
        f32x4 s1 = __builtin_amdgcn_mfma_f32_16x16x32_bf16(kf1, qf, z, 0, 0, 0);
        bf16x8 a8, vf;
#pragma unroll
        for (int t = 0; t < 4; ++t) {
            a8[t] = bftrunc(exp2f(s0[t]));
            a8[4 + t] = bftrunc(exp2f(s1[t]));
            vf[t] = v0[t];
            vf[4 + t] = v1[t];
        }
        acc = __builtin_amdgcn_mfma_f32_16x16x32_bf16(a8, vf, acc, 0, 0, 0);
        kf0 = nk0; kf1 = nk1; v0 = nv0; v1 = nv1;
    }

    {   // diagonal tile at k0d = nfull*32 (data already in kf/v regs)
        f32x4 s0 = __builtin_amdgcn_mfma_f32_16x16x32_bf16(kf0, qf, z, 0, 0, 0);
        bf16x8 a8, vf;
        if (q0 & 16) {                      // sub0 full, sub1 diagonal
            f32x4 s1 = __builtin_amdgcn_mfma_f32_16x16x32_bf16(kf1, qf, z, 0, 0, 0);
#pragma unroll
            for (int t = 0; t < 4; ++t) {
                a8[t] = bftrunc(exp2f(s0[t]));
                a8[4 + t] = (4 * g + t <= c) ? bftrunc(exp2f(s1[t])) : (short)0;
            }
        } else {                            // sub0 diagonal, sub1 empty
#pragma unroll
            for (int t = 0; t < 4; ++t) {
                a8[t] = (4 * g + t <= c) ? bftrunc(exp2f(s0[t])) : (short)0;
                a8[4 + t] = (short)0;
            }
        }
#pragma unroll
        for (int t = 0; t < 4; ++t) { vf[t] = v0[t]; vf[4 + t] = v1[t]; }
        acc = __builtin_amdgcn_mfma_f32_16x16x32_bf16(a8, vf, acc, 0, 0, 0);
    }

#pragma unroll
    for (int r = 0; r < 4; ++r)
        AObf[(size_t)(b * T_SEQ + q0 + 4 * g + r) * DMODEL + h * EHEAD + c] = f2bf(acc[r]);
}

// ---------------------------------------------------------------------------
// K4: ff1 = relu(AO @ W1 + b1) -> F bf16 [8192][512]. W1t[n][k] in registers.
// ---------------------------------------------------------------------------
__global__ __launch_bounds__(256) void k_ff1(const short* __restrict__ AObf,
                                             const short* __restrict__ W1t,
                                             const float* __restrict__ b1,
                                             short* __restrict__ F) {
    int nc = blockIdx.y;
    int wave = threadIdx.x >> 6, lane = threadIdx.x & 63;
    int g = lane >> 4, c = lane & 15;
    int row0 = blockIdx.x * 64 + wave * 16;

    bf16x8 wf[8][4];
#pragma unroll
    for (int nt = 0; nt < 8; ++nt)
#pragma unroll
        for (int kk = 0; kk < 4; ++kk)
            wf[nt][kk] = *(const bf16x8*)(W1t + (nc * 128 + nt * 16 + c) * 128 + kk * 32 + 8 * g);

    bf16x8 af[4];
#pragma unroll
    for (int kk = 0; kk < 4; ++kk)
        af[kk] = *(const bf16x8*)(AObf + (size_t)(row0 + c) * 128 + kk * 32 + 8 * g);

    f32x4 acc[8];
#pragma unroll
    for (int nt = 0; nt < 8; ++nt) acc[nt] = (f32x4){0.f, 0.f, 0.f, 0.f};
#pragma unroll
    for (int kk = 0; kk < 4; ++kk)
#pragma unroll
        for (int nt = 0; nt < 8; ++nt)
            acc[nt] = __builtin_amdgcn_mfma_f32_16x16x32_bf16(af[kk], wf[nt][kk], acc[nt], 0, 0, 0);

#pragma unroll
    for (int nt = 0; nt < 8; ++nt) {
        int col = nc * 128 + nt * 16 + c;
        float bb = b1[col];
#pragma unroll
        for (int r = 0; r < 4; ++r)
            F[(size_t)(row0 + 4 * g + r) * DFF + col] = f2bf(fmaxf(acc[nt][r] + bb, 0.f));
    }
}

// ---------------------------------------------------------------------------
// K5: out = F @ W2 + b2 + xpe. W2t[n][k=512] in registers (32-col groups).
// ---------------------------------------------------------------------------
__global__ __launch_bounds__(256) void k_ff2(const short* __restrict__ F,
                                             const short* __restrict__ W2t,
                                             const float* __restrict__ b2,
                                             const float* __restrict__ xpe,
                                             float* __restrict__ out) {
    int ng = blockIdx.y;
    int wave = threadIdx.x >> 6, lane = threadIdx.x & 63;
    int g = lane >> 4, c = lane & 15;
    int row0 = blockIdx.x * 64 + wave * 16;

    bf16x8 wf[2][16];
#pragma unroll
    for (int nt = 0; nt < 2; ++nt)
#pragma unroll
        for (int kk = 0; kk < 16; ++kk)
            wf[nt][kk] = *(const bf16x8*)(W2t + (ng * 32 + nt * 16 + c) * 512 + kk * 32 + 8 * g);

    f32x4 acc[2];
    acc[0] = (f32x4){0.f, 0.f, 0.f, 0.f};
    acc[1] = (f32x4){0.f, 0.f, 0.f, 0.f};
#pragma unroll
    for (int kk = 0; kk < 16; ++kk) {
        bf16x8 a = *(const bf16x8*)(F + (size_t)(row0 + c) * 512 + kk * 32 + 8 * g);
        acc[0] = __builtin_amdgcn_mfma_f32_16x16x32_bf16(a, wf[0][kk], acc[0], 0, 0, 0);
        acc[1] = __builtin_amdgcn_mfma_f32_16x16x32_bf16(a, wf[1][kk], acc[1], 0, 0, 0);
    }
#pragma unroll
    for (int nt = 0; nt < 2; ++nt) {
        int col = ng * 32 + nt * 16 + c;
        float bb = b2[col];
#pragma unroll
        for (int r = 0; r < 4; ++r) {
            size_t o = (size_t)(row0 + 4 * g + r) * DMODEL + col;
            out[o] = acc[nt][r] + bb + xpe[o];
        }
    }
}

// ---------------------------------------------------------------------------
extern "C" void kernel_launch(void* const* d_in, const int* in_sizes, int n_in,
                              void* d_out, int out_size, void* d_ws, size_t ws_size,
                              hipStream_t stream) {
    const float* x  = (const float*)d_in[0];
    const float* WQ = (const float*)d_in[1];
    const float* WK = (const float*)d_in[2];
    const float* WV = (const float*)d_in[3];
    const float* W1 = (const float*)d_in[4];
    const float* b1 = (const float*)d_in[5];
    const float* W2 = (const float*)d_in[6];
    const float* b2 = (const float*)d_in[7];
    float* out = (float*)d_out;

    const size_t NTD = (size_t)BATCH * T_SEQ * DMODEL;   // 1048576
    float* xpe   = (float*)d_ws;
    float* psum  = xpe + NTD;                            // 32*8*2048 = 524288
    short* xpe16 = (short*)(psum + 524288);
    short* Qp    = xpe16 + NTD;                          // [32][2048][32] padded
    short* Kp    = Qp + 2 * NTD;
    short* Vs    = Kp + 2 * NTD;
    short* AObf  = Vs + NTD;
    short* F     = AObf + NTD;                           // 8192*512 shorts
    short* Wqkvt = F + 4 * NTD;
    short* W1t   = Wqkvt + 3 * 16384;
    short* W2t   = W1t + 65536;

    k_pre<<<dim3(6848), dim3(256), 0, stream>>>(x, WQ, WK, WV, W1, W2,
                                                xpe, xpe16, Wqkvt, W1t, W2t,
                                                Qp, Kp);

    k_qkv<<<dim3(128, 3), dim3(256), 0, stream>>>(xpe16, Wqkvt, Qp, Kp, Vs);

    k_csum_part<<<dim3(16, 8, 32), dim3(256), 0, stream>>>(Qp, Kp, psum);

    k_csum_fin<<<dim3(16, 32), dim3(256), 0, stream>>>(psum, Vs);

    k_attn<<<dim3(32, 32), dim3(256), 0, stream>>>(Qp, Kp, Vs, AObf);

    k_ff1<<<dim3(128, 4), dim3(256), 0, stream>>>(AObf, W1t, b1, F);

    k_ff2<<<dim3(128, 4), dim3(256), 0, stream>>>(F, W2t, b2, xpe, out);
}

// Round 6
// 126.677 us; speedup vs baseline: 1.3501x; 1.3501x over previous
//
#include <hip/hip_runtime.h>
#include <math.h>
#include <stdint.h>

#define T_SEQ 2048
#define BATCH 4
#define DMODEL 128
#define DFF 512
#define NHEAD 8
#define EHEAD 16

#define RSQRT_T 0.022097086912079608f
#define QSCALE (0.022097086912079608f * 1.4426950408889634f)   // fold log2(e): use exp2

typedef __attribute__((ext_vector_type(8))) short bf16x8;
typedef __attribute__((ext_vector_type(4))) short bf16x4;
typedef __attribute__((ext_vector_type(4))) float f32x4;

__device__ __forceinline__ short f2bf(float f) {            // RNE
    uint32_t u = __float_as_uint(f);
    u = u + 0x7FFF + ((u >> 16) & 1);
    return (short)(u >> 16);
}
__device__ __forceinline__ short bftrunc(float f) {         // truncate (cheap)
    return (short)(__float_as_uint(f) >> 16);
}
__device__ __forceinline__ float bf2f(short s) {
    return __uint_as_float(((uint32_t)(unsigned short)s) << 16);
}

#define MFMA16(A, B, C) __builtin_amdgcn_mfma_f32_16x16x32_bf16(A, B, C, 0, 0, 0)

// ---------------------------------------------------------------------------
// K0: xpe = x + PE (fp32 + bf16 copies); transpose+convert all weights to bf16
// ---------------------------------------------------------------------------
__global__ __launch_bounds__(256) void k_pre(const float* __restrict__ x,
                                             const float* __restrict__ WQ,
                                             const float* __restrict__ WK,
                                             const float* __restrict__ WV,
                                             const float* __restrict__ W1,
                                             const float* __restrict__ W2,
                                             float* __restrict__ xpe,
                                             short* __restrict__ xpe16,
                                             short* __restrict__ Wqkvt,
                                             short* __restrict__ W1t,
                                             short* __restrict__ W2t) {
    int bid = blockIdx.x;
    int tid = threadIdx.x;
    if (bid < 4096) {                       // PE over B*T*D = 1M
        int idx = bid * 256 + tid;
        int f = idx & (DMODEL - 1);
        int t = (idx >> 7) & (T_SEQ - 1);
        float dv = __expf(-(float)(f & ~1) * (9.210340371976184f / 128.0f));
        float ang = (float)t * dv;
        float pe = (f & 1) ? __cosf(ang) : __sinf(ang);
        float v = x[idx] + pe;
        xpe[idx] = v;
        xpe16[idx] = f2bf(v);
    } else if (bid < 4288) {                // WQ/WK/WV -> [n][k] bf16
        int m = (bid - 4096) >> 6;
        int o = ((bid - 4096) & 63) * 256 + tid;      // 0..16383
        int n = o >> 7, k = o & 127;
        const float* W = (m == 0) ? WQ : (m == 1) ? WK : WV;
        Wqkvt[m * 16384 + o] = f2bf(W[k * 128 + n]);
    } else if (bid < 4544) {                // W1 [128][512] -> W1t [512][128]
        int o = (bid - 4288) * 256 + tid;   // 0..65535
        int n = o >> 7, k = o & 127;
        W1t[o] = f2bf(W1[k * 512 + n]);
    } else {                                // W2 [512][128] -> W2t [128][512]
        int o = (bid - 4544) * 256 + tid;   // 0..65535
        int n = o >> 9, k = o & 511;
        W2t[o] = f2bf(W2[k * 128 + n]);
    }
}

// ---------------------------------------------------------------------------
// K1: QKV projection: bf16 MFMA GEMM, W in registers (Wt[n][k] bf16).
// z=0: Qh[hb][t][16] *= QSCALE; z=1: Kh[hb][t][16]; z=2: Vs[hb][e][T]
// ---------------------------------------------------------------------------
__global__ __launch_bounds__(256) void k_qkv(const short* __restrict__ xpe16,
                                             const short* __restrict__ Wqkvt,
                                             short* __restrict__ Qh,
                                             short* __restrict__ Kh,
                                             short* __restrict__ Vs) {
    int z = blockIdx.y;
    const short* Wt = Wqkvt + z * 16384;
    int wave = threadIdx.x >> 6, lane = threadIdx.x & 63;
    int g = lane >> 4, c = lane & 15;
    int row0 = blockIdx.x * 64 + wave * 16;

    bf16x8 wf[8][4];
#pragma unroll
    for (int nt = 0; nt < 8; ++nt)
#pragma unroll
        for (int kk = 0; kk < 4; ++kk)
            wf[nt][kk] = *(const bf16x8*)(Wt + (nt * 16 + c) * 128 + kk * 32 + 8 * g);

    bf16x8 af[4];
#pragma unroll
    for (int kk = 0; kk < 4; ++kk)
        af[kk] = *(const bf16x8*)(xpe16 + (size_t)(row0 + c) * 128 + kk * 32 + 8 * g);

    f32x4 acc[8];
#pragma unroll
    for (int nt = 0; nt < 8; ++nt) acc[nt] = (f32x4){0.f, 0.f, 0.f, 0.f};
#pragma unroll
    for (int kk = 0; kk < 4; ++kk)
#pragma unroll
        for (int nt = 0; nt < 8; ++nt)
            acc[nt] = MFMA16(af[kk], wf[nt][kk], acc[nt]);

    int b = row0 >> 11;
    int t0 = (row0 & (T_SEQ - 1)) + 4 * g;
    if (z < 2) {
        short* dst = (z == 0) ? Qh : Kh;
        float sc = (z == 0) ? QSCALE : 1.0f;
#pragma unroll
        for (int nt = 0; nt < 8; ++nt) {
            int hb = nt * 4 + b;
#pragma unroll
            for (int r = 0; r < 4; ++r)
                dst[(size_t)(hb * T_SEQ + t0 + r) * 16 + c] = f2bf(acc[nt][r] * sc);
        }
    } else {
#pragma unroll
        for (int nt = 0; nt < 8; ++nt) {
            int hb = nt * 4 + b;
            bf16x4 v;
#pragma unroll
            for (int r = 0; r < 4; ++r) v[r] = f2bf(acc[nt][r]);
            *(bf16x4*)(Vs + (size_t)(hb * 16 + c) * T_SEQ + t0) = v;
        }
    }
}

// ---------------------------------------------------------------------------
// K2a: partial column sums, batched register-staged Q streaming.
// psum[hb][qc][ks][32] = sum over chunk's q (causal) of exp2(S'[q,k])
// grid (16, 8, 32): ks = bx*4+wave, qc = by, hb = bz. block 256.
// ---------------------------------------------------------------------------
struct QB8 { bf16x8 q[8]; };

__device__ __forceinline__ void load_q8(QB8& Q, const short* qp, int g, int n) {
    if (g < 2) {
#pragma unroll
        for (int i = 0; i < 8; ++i)
            if (i < n) Q.q[i] = *(const bf16x8*)(qp + i * 256);
    }
}
__device__ __forceinline__ void comp_q8(const QB8& Q, const bf16x8& kfA, const bf16x8& kfB,
                                        float& csA, float& csB, int n) {
    const f32x4 z = {0.f, 0.f, 0.f, 0.f};
#pragma unroll
    for (int i = 0; i < 8; ++i)
        if (i < n) {
            f32x4 sA = MFMA16(Q.q[i], kfA, z);
            f32x4 sB = MFMA16(Q.q[i], kfB, z);
#pragma unroll
            for (int r = 0; r < 4; ++r) {
                csA += exp2f(sA[r]);
                csB += exp2f(sB[r]);
            }
        }
}

__global__ __launch_bounds__(256) void k_csum_part(const short* __restrict__ Qh,
                                                   const short* __restrict__ Kh,
                                                   float* __restrict__ psum) {
    int wave = threadIdx.x >> 6, lane = threadIdx.x & 63;
    int g = lane >> 4, c = lane & 15;
    int ks = blockIdx.x * 4 + wave;
    int qc = blockIdx.y, hb = blockIdx.z;
    int k0 = ks * 32, qcs = qc * 256;
    if (k0 >= qcs + 256) return;            // chunk entirely above diagonal
    const size_t hbT = (size_t)hb * T_SEQ;
    const f32x4 z = {0.f, 0.f, 0.f, 0.f};
    const bf16x8 zz = {0, 0, 0, 0, 0, 0, 0, 0};

    bf16x8 kfA = zz, kfB = zz;
    if (g < 2) {
        kfA = *(const bf16x8*)(Kh + (hbT + k0 + c) * 16 + 8 * g);
        kfB = *(const bf16x8*)(Kh + (hbT + k0 + 16 + c) * 16 + 8 * g);
    }

    float csA = 0.f, csB = 0.f;
    int q0s;
    if (k0 >= qcs) {                        // diagonal tiles live in this chunk
        bf16x8 qf = zz, qf2 = zz;
        if (g < 2) {
            qf = *(const bf16x8*)(Qh + (hbT + k0 + c) * 16 + 8 * g);
            qf2 = *(const bf16x8*)(Qh + (hbT + k0 + 16 + c) * 16 + 8 * g);
        }
        f32x4 sA = MFMA16(qf, kfA, z);
#pragma unroll
        for (int r = 0; r < 4; ++r)
            csA += (4 * g + r >= c) ? exp2f(sA[r]) : 0.f;
        f32x4 sA2 = MFMA16(qf2, kfA, z);
        f32x4 sB2 = MFMA16(qf2, kfB, z);
#pragma unroll
        for (int r = 0; r < 4; ++r) {
            csA += exp2f(sA2[r]);
            csB += (4 * g + r >= c) ? exp2f(sB2[r]) : 0.f;
        }
        q0s = k0 + 32;
    } else {
        q0s = qcs;
    }
    int nt = (qcs + 256 - q0s) >> 4;        // 0..16 q-tiles remaining
    const short* qp = Qh + (hbT + q0s + c) * 16 + 8 * g;

    QB8 QA, QB_;
#pragma unroll
    for (int i = 0; i < 8; ++i) { QA.q[i] = zz; QB_.q[i] = zz; }

    int nbq = nt >> 3, rem = nt & 7;
    if (nbq >= 1) load_q8(QA, qp, g, 8);
    if (nbq >= 2) load_q8(QB_, qp + 2048, g, 8);
    if (nbq >= 1) comp_q8(QA, kfA, kfB, csA, csB, 8);
    if (nbq >= 2) comp_q8(QB_, kfA, kfB, csA, csB, 8);
    if (rem) {
        const short* qr = qp + nbq * 2048;
        load_q8(QA, qr, g, rem);
        comp_q8(QA, kfA, kfB, csA, csB, rem);
    }

    csA += __shfl_xor(csA, 16);
    csA += __shfl_xor(csA, 32);
    csB += __shfl_xor(csB, 16);
    csB += __shfl_xor(csB, 32);
    if (lane < 32)
        psum[((size_t)(hb * 8 + qc) * 64 + ks) * 32 + lane] =
            (lane < 16) ? csA : csB;
}

// ---------------------------------------------------------------------------
// K2b: reduce partials -> inv, scale V columns. grid (16, 32), block 256.
// ---------------------------------------------------------------------------
__global__ __launch_bounds__(256) void k_csum_fin(const float* __restrict__ psum,
                                                  short* __restrict__ Vs) {
    __shared__ float invl[128];
    int hb = blockIdx.y;
    int t = threadIdx.x;
    if (t < 128) {
        int k = blockIdx.x * 128 + t;
        int ks = k >> 5, j = k & 31;
        float s = 0.f;
        for (int qc = ks >> 3; qc < 8; ++qc)
            s += psum[((size_t)(hb * 8 + qc) * 64 + ks) * 32 + j];
        invl[t] = 1.0f / s;
    }
    __syncthreads();
    int e = t >> 4, kk = (t & 15) * 8;
    size_t vo = (size_t)(hb * 16 + e) * T_SEQ + blockIdx.x * 128 + kk;
    bf16x8 v = *(bf16x8*)(Vs + vo);
    bf16x8 o;
#pragma unroll
    for (int j = 0; j < 8; ++j) o[j] = f2bf(bf2f(v[j]) * invl[kk + j]);
    *(bf16x8*)(Vs + vo) = o;
}

// ---------------------------------------------------------------------------
// K3: attention output. Each wave owns 32 q-rows; K/V streamed via 4-tile
// register batches, double-buffered (load batch n+1, compute batch n).
// O[q] = sum_{k<=q} exp2(S') * Vs   (V pre-scaled by 1/colsum)
// grid (16, 32): s = bx*4+wave in [0,64), q0 = (63-s)*32 (longest first).
// ---------------------------------------------------------------------------
struct KVB4 {
    bf16x8 k0[4], k1[4];
    bf16x4 v0[4], v1[4];
};

__device__ __forceinline__ void load_kv4(KVB4& B, const short* kp, const short* vp, int g) {
    if (g < 2) {
#pragma unroll
        for (int i = 0; i < 4; ++i) {
            B.k0[i] = *(const bf16x8*)(kp + i * 512);
            B.k1[i] = *(const bf16x8*)(kp + i * 512 + 256);
        }
    }
#pragma unroll
    for (int i = 0; i < 4; ++i) {
        B.v0[i] = *(const bf16x4*)(vp + i * 32);
        B.v1[i] = *(const bf16x4*)(vp + i * 32 + 16);
    }
}

__device__ __forceinline__ void comp_slot(const bf16x8& kf0, const bf16x8& kf1,
                                          const bf16x4& v0, const bf16x4& v1,
                                          const bf16x8& qf0, const bf16x8& qf1,
                                          f32x4& acc0, f32x4& acc1) {
    const f32x4 z = {0.f, 0.f, 0.f, 0.f};
    f32x4 s0 = MFMA16(kf0, qf0, z);
    f32x4 s1 = MFMA16(kf1, qf0, z);
    f32x4 s2 = MFMA16(kf0, qf1, z);
    f32x4 s3 = MFMA16(kf1, qf1, z);
    bf16x8 aA, aB, vf;
#pragma unroll
    for (int t = 0; t < 4; ++t) {
        aA[t] = bftrunc(exp2f(s0[t]));
        aA[4 + t] = bftrunc(exp2f(s1[t]));
        aB[t] = bftrunc(exp2f(s2[t]));
        aB[4 + t] = bftrunc(exp2f(s3[t]));
        vf[t] = v0[t];
        vf[4 + t] = v1[t];
    }
    acc0 = MFMA16(aA, vf, acc0);
    acc1 = MFMA16(aB, vf, acc1);
}

__device__ __forceinline__ void comp_kv4(const KVB4& B, const bf16x8& qf0, const bf16x8& qf1,
                                         f32x4& acc0, f32x4& acc1) {
#pragma unroll
    for (int i = 0; i < 4; ++i)
        comp_slot(B.k0[i], B.k1[i], B.v0[i], B.v1[i], qf0, qf1, acc0, acc1);
}

__global__ __launch_bounds__(256) void k_attn(const short* __restrict__ Qh,
                                              const short* __restrict__ Kh,
                                              const short* __restrict__ Vs,
                                              short* __restrict__ AObf) {
    int hb = blockIdx.y, h = hb >> 2, b = hb & 3;
    int wave = threadIdx.x >> 6, lane = threadIdx.x & 63;
    int g = lane >> 4, c = lane & 15;
    int s = blockIdx.x * 4 + wave;
    int q0 = (63 - s) * 32;
    const size_t hbT = (size_t)hb * T_SEQ;
    const f32x4 z = {0.f, 0.f, 0.f, 0.f};
    const bf16x8 zz = {0, 0, 0, 0, 0, 0, 0, 0};

    bf16x8 qf0 = zz, qf1 = zz;
    if (g < 2) {
        qf0 = *(const bf16x8*)(Qh + (hbT + q0 + c) * 16 + 8 * g);
        qf1 = *(const bf16x8*)(Qh + (hbT + q0 + 16 + c) * 16 + 8 * g);
    }
    const short* kp = Kh + (hbT + c) * 16 + 8 * g;
    const short* vp = Vs + (size_t)(hb * 16 + c) * T_SEQ + 4 * g;

    int nfull = q0 >> 5;                    // full 32-k tiles before diagonal
    int nb = nfull >> 2;                    // batches of 4 tiles
    int rem = nfull & 3;

    f32x4 acc0 = z, acc1 = z;
    KVB4 A, Bb;
#pragma unroll
    for (int i = 0; i < 4; ++i) {           // zero pad lanes (g>=2) once
        A.k0[i] = zz; A.k1[i] = zz; Bb.k0[i] = zz; Bb.k1[i] = zz;
    }

    if (nb) {
        load_kv4(A, kp, vp, g); kp += 2048; vp += 128;
        int bt = 0;
        while (bt + 2 <= nb) {
            load_kv4(Bb, kp, vp, g); kp += 2048; vp += 128;
            comp_kv4(A, qf0, qf1, acc0, acc1);
            if (bt + 2 < nb) { load_kv4(A, kp, vp, g); kp += 2048; vp += 128; }
            comp_kv4(Bb, qf0, qf1, acc0, acc1);
            bt += 2;
        }
        if (bt < nb) comp_kv4(A, qf0, qf1, acc0, acc1);
    }

    // remainder full tiles (0..3), batched-guarded
#pragma unroll
    for (int i = 0; i < 3; ++i)
        if (i < rem) {
            if (g < 2) {
                A.k0[i] = *(const bf16x8*)(kp + i * 512);
                A.k1[i] = *(const bf16x8*)(kp + i * 512 + 256);
            }
            A.v0[i] = *(const bf16x4*)(vp + i * 32);
            A.v1[i] = *(const bf16x4*)(vp + i * 32 + 16);
        }
#pragma unroll
    for (int i = 0; i < 3; ++i)
        if (i < rem)
            comp_slot(A.k0[i], A.k1[i], A.v0[i], A.v1[i], qf0, qf1, acc0, acc1);
    kp += rem << 9;
    vp += rem << 5;

    {   // diagonal 32-k tile at k0 = q0
        bf16x8 kf0 = zz, kf1 = zz;
        if (g < 2) {
            kf0 = *(const bf16x8*)(kp);
            kf1 = *(const bf16x8*)(kp + 256);
        }
        bf16x4 v0 = *(const bf16x4*)(vp);
        bf16x4 v1 = *(const bf16x4*)(vp + 16);
        f32x4 s0 = MFMA16(kf0, qf0, z);
        f32x4 sB0 = MFMA16(kf0, qf1, z);
        f32x4 sB1 = MFMA16(kf1, qf1, z);
        bf16x8 aA, aB, vf;
#pragma unroll
        for (int t = 0; t < 4; ++t) {
            aA[t] = (4 * g + t <= c) ? bftrunc(exp2f(s0[t])) : (short)0;
            aA[4 + t] = (short)0;
            aB[t] = bftrunc(exp2f(sB0[t]));
            aB[4 + t] = (4 * g + t <= c) ? bftrunc(exp2f(sB1[t])) : (short)0;
            vf[t] = v0[t];
            vf[4 + t] = v1[t];
        }
        acc0 = MFMA16(aA, vf, acc0);
        acc1 = MFMA16(aB, vf, acc1);
    }

#pragma unroll
    for (int r = 0; r < 4; ++r) {
        AObf[(size_t)(b * T_SEQ + q0 + 4 * g + r) * DMODEL + h * EHEAD + c] = f2bf(acc0[r]);
        AObf[(size_t)(b * T_SEQ + q0 + 16 + 4 * g + r) * DMODEL + h * EHEAD + c] = f2bf(acc1[r]);
    }
}

// ---------------------------------------------------------------------------
// K4: ff1 = relu(AO @ W1 + b1) -> F bf16 [8192][512]. W1t[n][k] in registers.
// ---------------------------------------------------------------------------
__global__ __launch_bounds__(256) void k_ff1(const short* __restrict__ AObf,
                                             const short* __restrict__ W1t,
                                             const float* __restrict__ b1,
                                             short* __restrict__ F) {
    int nc = blockIdx.y;
    int wave = threadIdx.x >> 6, lane = threadIdx.x & 63;
    int g = lane >> 4, c = lane & 15;
    int row0 = blockIdx.x * 64 + wave * 16;

    bf16x8 wf[8][4];
#pragma unroll
    for (int nt = 0; nt < 8; ++nt)
#pragma unroll
        for (int kk = 0; kk < 4; ++kk)
            wf[nt][kk] = *(const bf16x8*)(W1t + (nc * 128 + nt * 16 + c) * 128 + kk * 32 + 8 * g);

    bf16x8 af[4];
#pragma unroll
    for (int kk = 0; kk < 4; ++kk)
        af[kk] = *(const bf16x8*)(AObf + (size_t)(row0 + c) * 128 + kk * 32 + 8 * g);

    f32x4 acc[8];
#pragma unroll
    for (int nt = 0; nt < 8; ++nt) acc[nt] = (f32x4){0.f, 0.f, 0.f, 0.f};
#pragma unroll
    for (int kk = 0; kk < 4; ++kk)
#pragma unroll
        for (int nt = 0; nt < 8; ++nt)
            acc[nt] = MFMA16(af[kk], wf[nt][kk], acc[nt]);

#pragma unroll
    for (int nt = 0; nt < 8; ++nt) {
        int col = nc * 128 + nt * 16 + c;
        float bb = b1[col];
#pragma unroll
        for (int r = 0; r < 4; ++r)
            F[(size_t)(row0 + 4 * g + r) * DFF + col] = f2bf(fmaxf(acc[nt][r] + bb, 0.f));
    }
}

// ---------------------------------------------------------------------------
// K5: out = F @ W2 + b2 + xpe. W2t[n][k=512] in registers (32-col groups).
// ---------------------------------------------------------------------------
__global__ __launch_bounds__(256) void k_ff2(const short* __restrict__ F,
                                             const short* __restrict__ W2t,
                                             const float* __restrict__ b2,
                                             const float* __restrict__ xpe,
                                             float* __restrict__ out) {
    int ng = blockIdx.y;
    int wave = threadIdx.x >> 6, lane = threadIdx.x & 63;
    int g = lane >> 4, c = lane & 15;
    int row0 = blockIdx.x * 64 + wave * 16;

    bf16x8 wf[2][16];
#pragma unroll
    for (int nt = 0; nt < 2; ++nt)
#pragma unroll
        for (int kk = 0; kk < 16; ++kk)
            wf[nt][kk] = *(const bf16x8*)(W2t + (ng * 32 + nt * 16 + c) * 512 + kk * 32 + 8 * g);

    f32x4 acc[2];
    acc[0] = (f32x4){0.f, 0.f, 0.f, 0.f};
    acc[1] = (f32x4){0.f, 0.f, 0.f, 0.f};
#pragma unroll
    for (int kk = 0; kk < 16; ++kk) {
        bf16x8 a = *(const bf16x8*)(F + (size_t)(row0 + c) * 512 + kk * 32 + 8 * g);
        acc[0] = MFMA16(a, wf[0][kk], acc[0]);
        acc[1] = MFMA16(a, wf[1][kk], acc[1]);
    }
#pragma unroll
    for (int nt = 0; nt < 2; ++nt) {
        int col = ng * 32 + nt * 16 + c;
        float bb = b2[col];
#pragma unroll
        for (int r = 0; r < 4; ++r) {
            size_t o = (size_t)(row0 + 4 * g + r) * DMODEL + col;
            out[o] = acc[nt][r] + bb + xpe[o];
        }
    }
}

// ---------------------------------------------------------------------------
extern "C" void kernel_launch(void* const* d_in, const int* in_sizes, int n_in,
                              void* d_out, int out_size, void* d_ws, size_t ws_size,
                              hipStream_t stream) {
    const float* x  = (const float*)d_in[0];
    const float* WQ = (const float*)d_in[1];
    const float* WK = (const float*)d_in[2];
    const float* WV = (const float*)d_in[3];
    const float* W1 = (const float*)d_in[4];
    const float* b1 = (const float*)d_in[5];
    const float* W2 = (const float*)d_in[6];
    const float* b2 = (const float*)d_in[7];
    float* out = (float*)d_out;

    const size_t NTD = (size_t)BATCH * T_SEQ * DMODEL;   // 1048576
    float* xpe   = (float*)d_ws;
    float* psum  = xpe + NTD;                            // 32*8*64*32 = 524288
    short* xpe16 = (short*)(psum + 524288);
    short* Qh    = xpe16 + NTD;
    short* Kh    = Qh + NTD;
    short* Vs    = Kh + NTD;
    short* AObf  = Vs + NTD;
    short* F     = AObf + NTD;                           // 8192*512 shorts
    short* Wqkvt = F + 4 * NTD;
    short* W1t   = Wqkvt + 3 * 16384;
    short* W2t   = W1t + 65536;

    k_pre<<<dim3(4800), dim3(256), 0, stream>>>(x, WQ, WK, WV, W1, W2,
                                                xpe, xpe16, Wqkvt, W1t, W2t);

    k_qkv<<<dim3(128, 3), dim3(256), 0, stream>>>(xpe16, Wqkvt, Qh, Kh, Vs);

    k_csum_part<<<dim3(16, 8, 32), dim3(256), 0, stream>>>(Qh, Kh, psum);

    k_csum_fin<<<dim3(16, 32), dim3(256), 0, stream>>>(psum, Vs);

    k_attn<<<dim3(16, 32), dim3(256), 0, stream>>>(Qh, Kh, Vs, AObf);

    k_ff1<<<dim3(128, 4), dim3(256), 0, stream>>>(AObf, W1t, b1, F);

    k_ff2<<<dim3(128, 4), dim3(256), 0, stream>>>(F, W2t, b2, xpe, out);
}

// Round 7
// 93.554 us; speedup vs baseline: 1.8281x; 1.3540x over previous
//
#include <hip/hip_runtime.h>
#include <math.h>
#include <stdint.h>

#define T_SEQ 2048
#define BATCH 4
#define DMODEL 128
#define DFF 512
#define NHEAD 8
#define EHEAD 16

#define QSCALE (0.022097086912079608f * 1.4426950408889634f)   // rsqrt(T) * log2(e)

typedef __attribute__((ext_vector_type(8))) short bf16x8;
typedef __attribute__((ext_vector_type(4))) short bf16x4;
typedef __attribute__((ext_vector_type(4))) float f32x4;

__device__ __forceinline__ short f2bf(float f) {            // RNE
    uint32_t u = __float_as_uint(f);
    u = u + 0x7FFF + ((u >> 16) & 1);
    return (short)(u >> 16);
}
__device__ __forceinline__ short bftrunc(float f) {         // truncate (cheap)
    return (short)(__float_as_uint(f) >> 16);
}
__device__ __forceinline__ float bf2f(short s) {
    return __uint_as_float(((uint32_t)(unsigned short)s) << 16);
}
__device__ __forceinline__ float exp2_fast(float x) {       // raw v_exp_f32
#if __has_builtin(__builtin_amdgcn_exp2f)
    return __builtin_amdgcn_exp2f(x);
#else
    float r; asm("v_exp_f32 %0, %1" : "=v"(r) : "v"(x)); return r;
#endif
}

#define MFMA16(A, B, C) __builtin_amdgcn_mfma_f32_16x16x32_bf16(A, B, C, 0, 0, 0)

__device__ __forceinline__ void gload16(const void* g, void* l) {
    __builtin_amdgcn_global_load_lds(
        (const __attribute__((address_space(1))) void*)g,
        (__attribute__((address_space(3))) void*)l, 16, 0, 0);
}

// ---------------------------------------------------------------------------
// K0: xpe = x + PE (fp32 + bf16 copies); transpose+convert all weights to bf16
// ---------------------------------------------------------------------------
__global__ __launch_bounds__(256) void k_pre(const float* __restrict__ x,
                                             const float* __restrict__ WQ,
                                             const float* __restrict__ WK,
                                             const float* __restrict__ WV,
                                             const float* __restrict__ W1,
                                             const float* __restrict__ W2,
                                             float* __restrict__ xpe,
                                             short* __restrict__ xpe16,
                                             short* __restrict__ Wqkvt,
                                             short* __restrict__ W1t,
                                             short* __restrict__ W2t) {
    int bid = blockIdx.x;
    int tid = threadIdx.x;
    if (bid < 4096) {                       // PE over B*T*D = 1M
        int idx = bid * 256 + tid;
        int f = idx & (DMODEL - 1);
        int t = (idx >> 7) & (T_SEQ - 1);
        float dv = __expf(-(float)(f & ~1) * (9.210340371976184f / 128.0f));
        float ang = (float)t * dv;
        float pe = (f & 1) ? __cosf(ang) : __sinf(ang);
        float v = x[idx] + pe;
        xpe[idx] = v;
        xpe16[idx] = f2bf(v);
    } else if (bid < 4288) {                // WQ/WK/WV -> [n][k] bf16
        int m = (bid - 4096) >> 6;
        int o = ((bid - 4096) & 63) * 256 + tid;      // 0..16383
        int n = o >> 7, k = o & 127;
        const float* W = (m == 0) ? WQ : (m == 1) ? WK : WV;
        Wqkvt[m * 16384 + o] = f2bf(W[k * 128 + n]);
    } else if (bid < 4544) {                // W1 [128][512] -> W1t [512][128]
        int o = (bid - 4288) * 256 + tid;   // 0..65535
        int n = o >> 7, k = o & 127;
        W1t[o] = f2bf(W1[k * 512 + n]);
    } else {                                // W2 [512][128] -> W2t [128][512]
        int o = (bid - 4544) * 256 + tid;   // 0..65535
        int n = o >> 9, k = o & 511;
        W2t[o] = f2bf(W2[k * 128 + n]);
    }
}

// ---------------------------------------------------------------------------
// K1: QKV projection: bf16 MFMA GEMM, W in registers (Wt[n][k] bf16).
// z=0: Qh[hb][t][16] *= QSCALE; z=1: Kh[hb][t][16]; z=2: Vs[hb][e][T]
// ---------------------------------------------------------------------------
__global__ __launch_bounds__(256) void k_qkv(const short* __restrict__ xpe16,
                                             const short* __restrict__ Wqkvt,
                                             short* __restrict__ Qh,
                                             short* __restrict__ Kh,
                                             short* __restrict__ Vs) {
    int z = blockIdx.y;
    const short* Wt = Wqkvt + z * 16384;
    int wave = threadIdx.x >> 6, lane = threadIdx.x & 63;
    int g = lane >> 4, c = lane & 15;
    int row0 = blockIdx.x * 64 + wave * 16;

    bf16x8 wf[8][4];
#pragma unroll
    for (int nt = 0; nt < 8; ++nt)
#pragma unroll
        for (int kk = 0; kk < 4; ++kk)
            wf[nt][kk] = *(const bf16x8*)(Wt + (nt * 16 + c) * 128 + kk * 32 + 8 * g);

    bf16x8 af[4];
#pragma unroll
    for (int kk = 0; kk < 4; ++kk)
        af[kk] = *(const bf16x8*)(xpe16 + (size_t)(row0 + c) * 128 + kk * 32 + 8 * g);

    f32x4 acc[8];
#pragma unroll
    for (int nt = 0; nt < 8; ++nt) acc[nt] = (f32x4){0.f, 0.f, 0.f, 0.f};
#pragma unroll
    for (int kk = 0; kk < 4; ++kk)
#pragma unroll
        for (int nt = 0; nt < 8; ++nt)
            acc[nt] = MFMA16(af[kk], wf[nt][kk], acc[nt]);

    int b = row0 >> 11;
    int t0 = (row0 & (T_SEQ - 1)) + 4 * g;
    if (z < 2) {
        short* dst = (z == 0) ? Qh : Kh;
        float sc = (z == 0) ? QSCALE : 1.0f;
#pragma unroll
        for (int nt = 0; nt < 8; ++nt) {
            int hb = nt * 4 + b;
#pragma unroll
            for (int r = 0; r < 4; ++r)
                dst[(size_t)(hb * T_SEQ + t0 + r) * 16 + c] = f2bf(acc[nt][r] * sc);
        }
    } else {
#pragma unroll
        for (int nt = 0; nt < 8; ++nt) {
            int hb = nt * 4 + b;
            bf16x4 v;
#pragma unroll
            for (int r = 0; r < 4; ++r) v[r] = f2bf(acc[nt][r]);
            *(bf16x4*)(Vs + (size_t)(hb * 16 + c) * T_SEQ + t0) = v;
        }
    }
}

// ---------------------------------------------------------------------------
// K2: column softmax denominators + V scaling, LDS-staged Q streaming.
// Block (kc, hb): 8 waves, wave w owns 32 cols kw = kc*256+w*32. Q tiles of
// 128 rows staged via global_load_lds double-buffer (waves 0-3 stage).
// After the sweep: invc -> LDS, then block scales Vs columns [kc*256, +256).
// ---------------------------------------------------------------------------
__global__ __launch_bounds__(512) void k_csum(const short* __restrict__ Qh,
                                              const short* __restrict__ Kh,
                                              short* __restrict__ Vs) {
    __shared__ __align__(16) short Qt[2][2048];
    __shared__ float invl[256];
    const bf16x8 zz = {0, 0, 0, 0, 0, 0, 0, 0};
    const f32x4 z = {0.f, 0.f, 0.f, 0.f};

    int kc = blockIdx.x, hb = blockIdx.y;
    int tid = threadIdx.x;
    int wave = tid >> 6, lane = tid & 63;
    int g = lane >> 4, c = lane & 15;
    int kw = kc * 256 + wave * 32;
    const size_t hbT = (size_t)hb * T_SEQ;
    const short* Qg = Qh + hbT * 16;

    bf16x8 kfA = zz, kfB = zz;
    if (g < 2) {
        kfA = *(const bf16x8*)(Kh + (hbT + kw + c) * 16 + 8 * g);
        kfB = *(const bf16x8*)(Kh + (hbT + kw + 16 + c) * 16 + 8 * g);
    }

    int tstart = 2 * kc;                    // first 128-q tile with q >= kc*256
    // prologue: stage tile tstart into buf 0 (waves 0-3 only)
    if (tid < 256)
        gload16(Qg + ((size_t)tstart * 128) * 16 + tid * 8, &Qt[0][tid * 8]);
    __syncthreads();

    float csA = 0.f, csB = 0.f;
    for (int tq = tstart; tq < 16; ++tq) {
        int buf = (tq - tstart) & 1;
        if (tq + 1 < 16 && tid < 256)
            gload16(Qg + ((size_t)(tq + 1) * 128) * 16 + tid * 8,
                    &Qt[buf ^ 1][tid * 8]);
        const short* Qtb = &Qt[buf][0];
#pragma unroll
        for (int ss = 0; ss < 4; ++ss) {
            int q32 = tq * 128 + ss * 32;
            if (q32 + 31 < kw) continue;            // fully above diagonal
            bf16x8 qfa = zz, qfb = zz;
            if (g < 2) {
                qfa = *(const bf16x8*)(Qtb + (ss * 32 + c) * 16 + g * 8);
                qfb = *(const bf16x8*)(Qtb + (ss * 32 + 16 + c) * 16 + g * 8);
            }
            f32x4 sA1 = MFMA16(qfa, kfA, z);
            f32x4 sB1 = MFMA16(qfa, kfB, z);
            f32x4 sA2 = MFMA16(qfb, kfA, z);
            f32x4 sB2 = MFMA16(qfb, kfB, z);
            if (q32 >= kw + 32) {                   // fully below diagonal
#pragma unroll
                for (int r = 0; r < 4; ++r) {
                    csA += exp2_fast(sA1[r]) + exp2_fast(sA2[r]);
                    csB += exp2_fast(sB1[r]) + exp2_fast(sB2[r]);
                }
            } else {                                // diagonal region: mask
                int kA = kw + c, kB = kw + 16 + c;
#pragma unroll
                for (int r = 0; r < 4; ++r) {
                    int qa = q32 + 4 * g + r, qb = q32 + 16 + 4 * g + r;
                    csA += (qa >= kA) ? exp2_fast(sA1[r]) : 0.f;
                    csA += (qb >= kA) ? exp2_fast(sA2[r]) : 0.f;
                    csB += (qa >= kB) ? exp2_fast(sB1[r]) : 0.f;
                    csB += (qb >= kB) ? exp2_fast(sB2[r]) : 0.f;
                }
            }
        }
        __syncthreads();
    }

    csA += __shfl_xor(csA, 16);
    csA += __shfl_xor(csA, 32);
    csB += __shfl_xor(csB, 16);
    csB += __shfl_xor(csB, 32);
    if (lane < 32)
        invl[wave * 32 + lane] = 1.0f / ((lane < 16) ? csA : csB);
    __syncthreads();

    // scale V columns [kc*256, +256): 512 threads x 8 shorts = 16e x 256k
    int e = tid >> 5, kcol = (tid & 31) * 8;
    size_t vo = (size_t)(hb * 16 + e) * T_SEQ + kc * 256 + kcol;
    bf16x8 v = *(bf16x8*)(Vs + vo);
    bf16x8 o;
#pragma unroll
    for (int j = 0; j < 8; ++j) o[j] = f2bf(bf2f(v[j]) * invl[kcol + j]);
    *(bf16x8*)(Vs + vo) = o;
}

// ---------------------------------------------------------------------------
// K3: attention output, LDS-staged K/V streaming.
// Block (bx, hb): qc = 7-bx; 8 waves, wave w owns 32 q-rows q0w = qc*256+w*32.
// K/V tiles of 128 k staged double-buffered: waves 0-3 stage K (linear 4KB),
// waves 4-7 stage V (e-major, XOR-swizzled global source -> conflict-free
// ds_read_b64). O[q] = sum_{k<=q} exp2(S') * Vs (V pre-scaled by 1/colsum).
// ---------------------------------------------------------------------------
__global__ __launch_bounds__(512) void k_attn(const short* __restrict__ Qh,
                                              const short* __restrict__ Kh,
                                              const short* __restrict__ Vs,
                                              short* __restrict__ AObf) {
    __shared__ __align__(16) short Kt[2][2048];
    __shared__ __align__(16) short Vt[2][2048];
    const bf16x8 zz = {0, 0, 0, 0, 0, 0, 0, 0};
    const f32x4 z = {0.f, 0.f, 0.f, 0.f};

    int hb = blockIdx.y, h = hb >> 2, b = hb & 3;
    int qc = 7 - (int)blockIdx.x;
    int tid = threadIdx.x;
    int wave = tid >> 6, lane = tid & 63;
    int g = lane >> 4, c = lane & 15;
    int q0w = qc * 256 + wave * 32;
    const size_t hbT = (size_t)hb * T_SEQ;
    const short* Kg = Kh + hbT * 16;
    const short* Vg = Vs + (size_t)hb * 16 * T_SEQ;

    bf16x8 qf0 = zz, qf1 = zz;
    if (g < 2) {
        qf0 = *(const bf16x8*)(Qh + (hbT + q0w + c) * 16 + 8 * g);
        qf1 = *(const bf16x8*)(Qh + (hbT + q0w + 16 + c) * 16 + 8 * g);
    }

    int nT = 2 * qc + 2;                    // 128-k tiles this block touches

    // stage helper (inline): tile kt -> buffer bf
#define STAGE(bf, kt)                                                        \
    do {                                                                     \
        int k0s = (kt) * 128;                                                \
        if (tid < 256) {                                                     \
            gload16(Kg + (size_t)k0s * 16 + tid * 8, &Kt[bf][tid * 8]);      \
        } else {                                                             \
            int t2 = tid - 256;                                              \
            int e = t2 >> 4, jp = t2 & 15, j = jp ^ (e & 7);                 \
            gload16(Vg + (size_t)e * T_SEQ + k0s + j * 8, &Vt[bf][t2 * 8]);  \
        }                                                                    \
    } while (0)

    STAGE(0, 0);
    __syncthreads();

    f32x4 acc0 = z, acc1 = z;
    for (int t = 0; t < nT; ++t) {
        int buf = t & 1;
        if (t + 1 < nT) STAGE(buf ^ 1, t + 1);
        const short* Ktb = &Kt[buf][0];
        const short* Vtb = &Vt[buf][0];
        if (t * 128 <= q0w + 31) {
#pragma unroll
            for (int ss = 0; ss < 4; ++ss) {
                int k32 = t * 128 + ss * 32;
                if (k32 > q0w + 31) continue;       // above causal range
                bf16x8 kf0 = zz, kf1 = zz;
                if (g < 2) {
                    kf0 = *(const bf16x8*)(Ktb + (ss * 32 + c) * 16 + g * 8);
                    kf1 = *(const bf16x8*)(Ktb + (ss * 32 + 16 + c) * 16 + g * 8);
                }
                int ja = ss * 4 + (g >> 1);
                const short* vrow = Vtb + c * 128 + ((g & 1) << 2);
                bf16x4 v0 = *(const bf16x4*)(vrow + ((ja ^ (c & 7)) << 3));
                bf16x4 v1 = *(const bf16x4*)(vrow + (((ja + 2) ^ (c & 7)) << 3));
                f32x4 s0 = MFMA16(kf0, qf0, z);
                f32x4 s1 = MFMA16(kf1, qf0, z);
                f32x4 s2 = MFMA16(kf0, qf1, z);
                f32x4 s3 = MFMA16(kf1, qf1, z);
                bf16x8 aA, aB, vf;
                if (k32 + 31 <= q0w) {              // full pair, no masking
#pragma unroll
                    for (int r = 0; r < 4; ++r) {
                        aA[r] = bftrunc(exp2_fast(s0[r]));
                        aA[4 + r] = bftrunc(exp2_fast(s1[r]));
                        aB[r] = bftrunc(exp2_fast(s2[r]));
                        aB[4 + r] = bftrunc(exp2_fast(s3[r]));
                        vf[r] = v0[r];
                        vf[4 + r] = v1[r];
                    }
                } else {                            // causal boundary: mask
                    int qa = q0w + c, qb = q0w + 16 + c;
                    int ka = k32 + 4 * g, kb = k32 + 16 + 4 * g;
#pragma unroll
                    for (int r = 0; r < 4; ++r) {
                        aA[r] = (ka + r <= qa) ? bftrunc(exp2_fast(s0[r])) : (short)0;
                        aA[4 + r] = (kb + r <= qa) ? bftrunc(exp2_fast(s1[r])) : (short)0;
                        aB[r] = (ka + r <= qb) ? bftrunc(exp2_fast(s2[r])) : (short)0;
                        aB[4 + r] = (kb + r <= qb) ? bftrunc(exp2_fast(s3[r])) : (short)0;
                        vf[r] = v0[r];
                        vf[4 + r] = v1[r];
                    }
                }
                acc0 = MFMA16(aA, vf, acc0);
                acc1 = MFMA16(aB, vf, acc1);
            }
        }
        __syncthreads();
    }
#undef STAGE

#pragma unroll
    for (int r = 0; r < 4; ++r) {
        AObf[(size_t)(b * T_SEQ + q0w + 4 * g + r) * DMODEL + h * EHEAD + c] = f2bf(acc0[r]);
        AObf[(size_t)(b * T_SEQ + q0w + 16 + 4 * g + r) * DMODEL + h * EHEAD + c] = f2bf(acc1[r]);
    }
}

// ---------------------------------------------------------------------------
// K4: ff1 = relu(AO @ W1 + b1) -> F bf16 [8192][512]. W1t[n][k] in registers.
// ---------------------------------------------------------------------------
__global__ __launch_bounds__(256) void k_ff1(const short* __restrict__ AObf,
                                             const short* __restrict__ W1t,
                                             const float* __restrict__ b1,
                                             short* __restrict__ F) {
    int nc = blockIdx.y;
    int wave = threadIdx.x >> 6, lane = threadIdx.x & 63;
    int g = lane >> 4, c = lane & 15;
    int row0 = blockIdx.x * 64 + wave * 16;

    bf16x8 wf[8][4];
#pragma unroll
    for (int nt = 0; nt < 8; ++nt)
#pragma unroll
        for (int kk = 0; kk < 4; ++kk)
            wf[nt][kk] = *(const bf16x8*)(W1t + (nc * 128 + nt * 16 + c) * 128 + kk * 32 + 8 * g);

    bf16x8 af[4];
#pragma unroll
    for (int kk = 0; kk < 4; ++kk)
        af[kk] = *(const bf16x8*)(AObf + (size_t)(row0 + c) * 128 + kk * 32 + 8 * g);

    f32x4 acc[8];
#pragma unroll
    for (int nt = 0; nt < 8; ++nt) acc[nt] = (f32x4){0.f, 0.f, 0.f, 0.f};
#pragma unroll
    for (int kk = 0; kk < 4; ++kk)
#pragma unroll
        for (int nt = 0; nt < 8; ++nt)
            acc[nt] = MFMA16(af[kk], wf[nt][kk], acc[nt]);

#pragma unroll
    for (int nt = 0; nt < 8; ++nt) {
        int col = nc * 128 + nt * 16 + c;
        float bb = b1[col];
#pragma unroll
        for (int r = 0; r < 4; ++r)
            F[(size_t)(row0 + 4 * g + r) * DFF + col] = f2bf(fmaxf(acc[nt][r] + bb, 0.f));
    }
}

// ---------------------------------------------------------------------------
// K5: out = F @ W2 + b2 + xpe. W2t[n][k=512] in registers (32-col groups).
// ---------------------------------------------------------------------------
__global__ __launch_bounds__(256) void k_ff2(const short* __restrict__ F,
                                             const short* __restrict__ W2t,
                                             const float* __restrict__ b2,
                                             const float* __restrict__ xpe,
                                             float* __restrict__ out) {
    int ng = blockIdx.y;
    int wave = threadIdx.x >> 6, lane = threadIdx.x & 63;
    int g = lane >> 4, c = lane & 15;
    int row0 = blockIdx.x * 64 + wave * 16;

    bf16x8 wf[2][16];
#pragma unroll
    for (int nt = 0; nt < 2; ++nt)
#pragma unroll
        for (int kk = 0; kk < 16; ++kk)
            wf[nt][kk] = *(const bf16x8*)(W2t + (ng * 32 + nt * 16 + c) * 512 + kk * 32 + 8 * g);

    f32x4 acc[2];
    acc[0] = (f32x4){0.f, 0.f, 0.f, 0.f};
    acc[1] = (f32x4){0.f, 0.f, 0.f, 0.f};
#pragma unroll
    for (int kk = 0; kk < 16; ++kk) {
        bf16x8 a = *(const bf16x8*)(F + (size_t)(row0 + c) * 512 + kk * 32 + 8 * g);
        acc[0] = MFMA16(a, wf[0][kk], acc[0]);
        acc[1] = MFMA16(a, wf[1][kk], acc[1]);
    }
#pragma unroll
    for (int nt = 0; nt < 2; ++nt) {
        int col = ng * 32 + nt * 16 + c;
        float bb = b2[col];
#pragma unroll
        for (int r = 0; r < 4; ++r) {
            size_t o = (size_t)(row0 + 4 * g + r) * DMODEL + col;
            out[o] = acc[nt][r] + bb + xpe[o];
        }
    }
}

// ---------------------------------------------------------------------------
extern "C" void kernel_launch(void* const* d_in, const int* in_sizes, int n_in,
                              void* d_out, int out_size, void* d_ws, size_t ws_size,
                              hipStream_t stream) {
    const float* x  = (const float*)d_in[0];
    const float* WQ = (const float*)d_in[1];
    const float* WK = (const float*)d_in[2];
    const float* WV = (const float*)d_in[3];
    const float* W1 = (const float*)d_in[4];
    const float* b1 = (const float*)d_in[5];
    const float* W2 = (const float*)d_in[6];
    const float* b2 = (const float*)d_in[7];
    float* out = (float*)d_out;

    const size_t NTD = (size_t)BATCH * T_SEQ * DMODEL;   // 1048576
    float* xpe   = (float*)d_ws;
    short* xpe16 = (short*)(xpe + NTD);
    short* Qh    = xpe16 + NTD;
    short* Kh    = Qh + NTD;
    short* Vs    = Kh + NTD;
    short* AObf  = Vs + NTD;
    short* F     = AObf + NTD;                           // 8192*512 shorts
    short* Wqkvt = F + 4 * NTD;
    short* W1t   = Wqkvt + 3 * 16384;
    short* W2t   = W1t + 65536;

    k_pre<<<dim3(4800), dim3(256), 0, stream>>>(x, WQ, WK, WV, W1, W2,
                                                xpe, xpe16, Wqkvt, W1t, W2t);

    k_qkv<<<dim3(128, 3), dim3(256), 0, stream>>>(xpe16, Wqkvt, Qh, Kh, Vs);

    k_csum<<<dim3(8, 32), dim3(512), 0, stream>>>(Qh, Kh, Vs);

    k_attn<<<dim3(8, 32), dim3(512), 0, stream>>>(Qh, Kh, Vs, AObf);

    k_ff1<<<dim3(128, 4), dim3(256), 0, stream>>>(AObf, W1t, b1, F);

    k_ff2<<<dim3(128, 4), dim3(256), 0, stream>>>(F, W2t, b2, xpe, out);
}